// Round 4
// baseline (1662.088 us; speedup 1.0000x reference)
//
#include <hip/hip_runtime.h>
#include <hip/hip_bf16.h>

// MPNScoreModule: B=8 graphs, N=64 nodes, E=256 edges, L=128, S=2 steps.
// Round 4: round-3 VALU scaffold unchanged except OUTPUT IS FLOAT32.
// (Evidence: threshold = 2% of max|ref| with no bf16 floor => _any_bf16
// false => fp32 in/out. Rounds 2/3 failed with identical absmax 6.28125 =
// max|ref| over the unwritten second half of the fp32 out buffer.)

typedef __attribute__((ext_vector_type(8))) __bf16 bf16x8;
typedef __attribute__((ext_vector_type(4))) __bf16 bf16x4;

__device__ __forceinline__ float leaky(float x) { return x > 0.f ? x : 0.01f * x; }

// ---- workspace layout (bytes) ----
#define WS_WT32   0          // f32 [10][128][128] transposed weights (s*5 + {W1,W2,W3,Wn1,Wn2}), [f][k]
#define WS_XAP    655360     // f32 [8][64][128]  x @ Wne[0:128] + b_node_enc
#define WS_XDP    917504     // f32 [8][64][128]  x @ Wne[128:256]
#define WS_EE0    1179648    // bf16 [8][256][128] leaky(edge_attr @ Wee + b)
#define WS_CE     1703936    // f32 [8][2][128]   gg @ W4  + b_edge_upd
#define WS_CN     1712128    // f32 [8][2][128]   gg @ Wn3 + b_node_upd
#define WS_CSROFF 1720320    // int [8][72]
#define WS_CSREID 1722624    // int [8][256]
// end ~1.73 MB

#define LDE 136   // padded LDS row stride (elements)

// ============================ prep kernel ============================
__global__ __launch_bounds__(256) void mpn_prep(
    const float* __restrict__ x,     // [8][64][128]
    const float* __restrict__ ea,    // [8][256][128]
    const float* __restrict__ u,     // [8][128]
    const int*   __restrict__ eidx,  // [8][2][256]
    const float* __restrict__ Wne,   // [257][128]
    const float* __restrict__ bne,   // [128]
    const float* __restrict__ Wee,   // [128][128]
    const float* __restrict__ bee,   // [128]
    const float* __restrict__ Wge,   // [128][128]
    const float* __restrict__ bge,   // [128]
    const float* __restrict__ Weu,   // [2][512][128]
    const float* __restrict__ beu,   // [2][128]
    const float* __restrict__ Wnu,   // [2][384][128]
    const float* __restrict__ bnu,   // [2][128]
    char* __restrict__ ws)
{
  const int b = blockIdx.x, tid = threadIdx.x;
  float*  wt  = (float*)(ws + WS_WT32);
  float*  xap = (float*)(ws + WS_XAP);
  float*  xdp = (float*)(ws + WS_XDP);
  __bf16* ee0 = (__bf16*)(ws + WS_EE0);
  float*  cev = (float*)(ws + WS_CE);
  float*  cnv = (float*)(ws + WS_CN);
  int* csroff = (int*)(ws + WS_CSROFF);
  int* csreid = (int*)(ws + WS_CSREID);

  if (b < 20) {
    // transpose the 10 [128][128] weight blocks: wt[m][f][k] = src[k][f]
    const int m = b >> 1, half = b & 1;
    const int s = m / 5, t = m % 5;
    const float* src = (t < 3) ? (Weu + (size_t)(s*512 + t*128)*128)
                               : (Wnu + (size_t)(s*384 + (t-3)*128)*128);
    const int f = half*64 + (tid & 63);
    const int kq = tid >> 6;
    for (int j = 0; j < 32; ++j) {
      int k = kq*32 + j;
      wt[m*16384 + f*128 + k] = src[k*128 + f];
    }
  } else if (b < 28) {
    // per-graph: gg, ce/cn constant vectors, CSR (deterministic)
    const int g = b - 20;
    __shared__ float gg_sh[128];
    __shared__ int dst_sh[256];
    __shared__ int cnt_sh[64];
    __shared__ int off_sh[65];
    if (tid < 128) {
      float acc = bge[tid];
      for (int k = 0; k < 128; ++k)
        acc += u[g*128 + k] * Wge[k*128 + tid];
      gg_sh[tid] = leaky(acc);
    }
    dst_sh[tid] = eidx[g*512 + 256 + tid];
    __syncthreads();
    {
      const int s = tid >> 7, f = tid & 127;
      float ac = beu[s*128 + f];
      float an = bnu[s*128 + f];
      for (int k = 0; k < 128; ++k) {
        float gk = gg_sh[k];
        ac += gk * Weu[(s*512 + 384 + k)*128 + f];
        an += gk * Wnu[(s*384 + 256 + k)*128 + f];
      }
      cev[(g*2 + s)*128 + f] = ac;
      cnv[(g*2 + s)*128 + f] = an;
    }
    if (tid < 64) {
      int c = 0;
      for (int e = 0; e < 256; ++e) c += (dst_sh[e] == tid) ? 1 : 0;
      cnt_sh[tid] = c;
    }
    __syncthreads();
    if (tid == 0) {
      int o = 0;
      for (int n = 0; n < 64; ++n) { off_sh[n] = o; o += cnt_sh[n]; }
      off_sh[64] = o;
    }
    __syncthreads();
    if (tid < 65) csroff[g*72 + tid] = off_sh[tid];
    if (tid < 64) {
      int o = off_sh[tid];
      for (int e = 0; e < 256; ++e)
        if (dst_sh[e] == tid) csreid[g*256 + (o++)] = e;
    }
  } else {
    // encoders: ee0 (16 blocks/graph), xap (4), xdp (4)
    const int bb = b - 28;
    const int g = bb / 24, r = bb % 24;
    const int f = tid & 127, rh = tid >> 7;
    if (r < 16) {
      const int row0 = r*16;
      for (int jj = 0; jj < 8; ++jj) {
        int row = row0 + rh + 2*jj;
        float acc = bee[f];
        for (int k = 0; k < 128; ++k)
          acc += ea[(g*256 + row)*128 + k] * Wee[k*128 + f];
        ee0[(g*256 + row)*128 + f] = (__bf16)leaky(acc);
      }
    } else if (r < 20) {
      const int row0 = (r - 16)*16;
      for (int jj = 0; jj < 8; ++jj) {
        int row = row0 + rh + 2*jj;
        float acc = bne[f];
        for (int k = 0; k < 128; ++k)
          acc += x[(g*64 + row)*128 + k] * Wne[k*128 + f];
        xap[(g*64 + row)*128 + f] = acc;
      }
    } else {
      const int row0 = (r - 20)*16;
      for (int jj = 0; jj < 8; ++jj) {
        int row = row0 + rh + 2*jj;
        float acc = 0.f;
        for (int k = 0; k < 128; ++k)
          acc += x[(g*64 + row)*128 + k] * Wne[(128 + k)*128 + f];
        xdp[(g*64 + row)*128 + f] = acc;
      }
    }
  }
}

// ============================ main kernel ============================
__global__ __launch_bounds__(256, 1) void mpn_main(
    const float* __restrict__ spdist,  // [8][64][64]
    const int*   __restrict__ eidx,    // [8][2][256]
    const float* __restrict__ Wne,     // row 256 = spdist weight
    const float* __restrict__ wscore,  // [128]
    const float* __restrict__ bscore,  // [1]
    const char* __restrict__ ws,
    float* __restrict__ out)           // [8][256][64]  (g*16384 + e*64 + d), FLOAT32
{
  __shared__ __align__(16) __bf16 s_ee[256*LDE];   // edge state
  __shared__ __align__(16) __bf16 s_h [64*LDE];    // node state
  __shared__ __align__(16) __bf16 s_p2[64*LDE];    // h@W2 (reused as agg)
  __shared__ __align__(16) __bf16 s_p3[64*LDE];    // h@W3 + ce (reused as h-scratch)
  __shared__ int s_off[65];
  __shared__ int s_eid[256];

  const float*  wt  = (const float*)(ws + WS_WT32);
  const float*  xap = (const float*)(ws + WS_XAP);
  const float*  xdp = (const float*)(ws + WS_XDP);
  const __bf16* ee0 = (const __bf16*)(ws + WS_EE0);
  const float*  cev = (const float*)(ws + WS_CE);
  const float*  cnv = (const float*)(ws + WS_CN);
  const int* csroff = (const int*)(ws + WS_CSROFF);
  const int* csreid = (const int*)(ws + WS_CSREID);

  const int tid = threadIdx.x;
  const int w = tid >> 6, l = tid & 63;
  const int g = blockIdx.x >> 6, d = blockIdx.x & 63;

  if (tid < 65) s_off[tid] = csroff[g*72 + tid];
  s_eid[tid] = csreid[g*256 + tid];

  // node encoder: h[i][f] = leaky(xap[i][f] + xdp[d][f] + sp(d,i)*wsp[f])
  {
    const int f = tid & 127, ib = tid >> 7;
    float xdpv = xdp[(g*64 + d)*128 + f];
    float wspv = Wne[256*128 + f];
    #pragma unroll
    for (int j = 0; j < 32; ++j) {
      int i = ib + 2*j;
      float sp = spdist[(g*64 + d)*64 + i];
      float v = xap[(g*64 + i)*128 + f] + xdpv + sp*wspv;
      s_h[i*LDE + f] = (__bf16)leaky(v);
    }
  }
  // stage ee0 -> LDS
  #pragma unroll
  for (int it = 0; it < 16; ++it) {
    int c = it*256 + tid;
    int row = c >> 4, col = c & 15;
    *(bf16x8*)&s_ee[row*LDE + col*8] = *(const bf16x8*)&ee0[(g*256 + row)*128 + col*8];
  }
  const int se = eidx[g*512 + tid];        // src of edge `tid`
  const int de = eidx[g*512 + 256 + tid];  // dst of edge `tid`
  __syncthreads();

  for (int s = 0; s < 2; ++s) {
    const float* W1 = wt + (s*5 + 0)*16384;
    const float* W2 = wt + (s*5 + 1)*16384;
    const float* W3 = wt + (s*5 + 2)*16384;
    const float* N1 = wt + (s*5 + 3)*16384;
    const float* N2 = wt + (s*5 + 4)*16384;

    // ---- phase 1: p2 = h@W2 ; p3 = h@W3 + ce
    {
      const int i = tid & 63, fq = tid >> 6;
      float hr[128];
      #pragma unroll
      for (int k = 0; k < 128; ++k) hr[k] = (float)s_h[i*LDE + k];
      for (int fi = 0; fi < 32; ++fi) {
        const int f = fq*32 + fi;
        float a2 = 0.f, a3 = 0.f;
        #pragma unroll
        for (int k = 0; k < 128; ++k) {
          a2 += hr[k] * W2[f*128 + k];
          a3 += hr[k] * W3[f*128 + k];
        }
        s_p2[i*LDE + f] = (__bf16)a2;
        s_p3[i*LDE + f] = (__bf16)(a3 + cev[(g*2 + s)*128 + f]);
      }
    }
    __syncthreads();

    // ---- phase 2: ee[e] += leaky(ee[e]@W1 + p2[src[e]] + p3[dst[e]]), e = tid.
    {
      float eer[128];
      #pragma unroll
      for (int k = 0; k < 128; ++k) eer[k] = (float)s_ee[tid*LDE + k];
      for (int f = 0; f < 128; ++f) {
        float acc = 0.f;
        #pragma unroll
        for (int k = 0; k < 128; ++k) acc += eer[k] * W1[f*128 + k];
        float vv = acc + (float)s_p2[se*LDE + f] + (float)s_p3[de*LDE + f];
        float old = (float)s_ee[tid*LDE + f];
        s_ee[tid*LDE + f] = (__bf16)(old + leaky(vv));
      }
    }
    __syncthreads();

    if (s == 0) {  // last step's node update is unused -> skip
      // ---- phase 3: agg = segment_sum(ee, dst) -> s_p2 (bf16)
      {
        const int node = w*16 + (l >> 2);
        const int fs = (l & 3)*32;
        float av[32];
        #pragma unroll
        for (int j = 0; j < 32; ++j) av[j] = 0.f;
        const int b0 = s_off[node], b1 = s_off[node + 1];
        for (int idx = b0; idx < b1; ++idx) {
          int e = s_eid[idx];
          #pragma unroll
          for (int cc = 0; cc < 4; ++cc) {
            bf16x8 vv = *(const bf16x8*)&s_ee[e*LDE + fs + cc*8];
            #pragma unroll
            for (int j = 0; j < 8; ++j) av[cc*8 + j] += (float)vv[j];
          }
        }
        #pragma unroll
        for (int cc = 0; cc < 4; ++cc) {
          bf16x8 o;
          #pragma unroll
          for (int j = 0; j < 8; ++j) o[j] = (__bf16)av[cc*8 + j];
          *(bf16x8*)&s_p2[node*LDE + fs + cc*8] = o;
        }
      }
      __syncthreads();
      // ---- phase 4: hnew = h + leaky(h@N1 + agg@N2 + cn) -> s_p3 scratch
      {
        const int i = tid & 63, fq = tid >> 6;
        float hr[128];
        #pragma unroll
        for (int k = 0; k < 128; ++k) hr[k] = (float)s_h[i*LDE + k];
        for (int fi = 0; fi < 32; ++fi) {
          const int f = fq*32 + fi;
          float acc = 0.f;
          #pragma unroll
          for (int k = 0; k < 128; ++k) acc += hr[k] * N1[f*128 + k];
          #pragma unroll
          for (int k = 0; k < 128; ++k) {
            int kk = (k + 2*(tid & 63)) & 127;
            acc += (float)s_p2[i*LDE + kk] * N2[f*128 + kk];
          }
          float old = (float)s_h[i*LDE + f];
          s_p3[i*LDE + f] = (__bf16)(old + leaky(acc + cnv[(g*2 + s)*128 + f]));
        }
      }
      __syncthreads();
      // copy scratch -> s_h
      #pragma unroll
      for (int it = 0; it < 8; ++it) {
        int c = it*256 + tid;
        int row = c >> 5, f4 = (c & 31)*4;
        *(bf16x4*)&s_h[row*LDE + f4] = *(const bf16x4*)&s_p3[row*LDE + f4];
      }
      __syncthreads();
    }
  }

  // ---- scores: out[g, e, d] = ee[e] . wscore + b   (float32 output!)
  {
    const int e = w*64 + l;
    float acc = bscore[0];
    #pragma unroll
    for (int k = 0; k < 128; ++k)
      acc += (float)s_ee[e*LDE + k] * wscore[k];
    out[g*16384 + e*64 + d] = acc;
  }
}

extern "C" void kernel_launch(void* const* d_in, const int* in_sizes, int n_in,
                              void* d_out, int out_size, void* d_ws, size_t ws_size,
                              hipStream_t stream) {
  (void)in_sizes; (void)n_in; (void)out_size; (void)ws_size;
  const float* x   = (const float*)d_in[0];
  const float* ea  = (const float*)d_in[1];
  const float* u   = (const float*)d_in[2];
  const float* sp  = (const float*)d_in[3];
  const int*   ei  = (const int*)d_in[4];
  const float* Wne = (const float*)d_in[5];
  const float* bne = (const float*)d_in[6];
  const float* Wee = (const float*)d_in[7];
  const float* bee = (const float*)d_in[8];
  const float* Wge = (const float*)d_in[9];
  const float* bge = (const float*)d_in[10];
  const float* Weu = (const float*)d_in[11];
  const float* beu = (const float*)d_in[12];
  const float* Wnu = (const float*)d_in[13];
  const float* bnu = (const float*)d_in[14];
  const float* Wsc = (const float*)d_in[15];
  const float* bsc = (const float*)d_in[16];
  char* ws = (char*)d_ws;

  hipLaunchKernelGGL(mpn_prep, dim3(220), dim3(256), 0, stream,
                     x, ea, u, ei, Wne, bne, Wee, bee, Wge, bge, Weu, beu, Wnu, bnu, ws);
  hipLaunchKernelGGL(mpn_main, dim3(512), dim3(256), 0, stream,
                     sp, ei, Wne, Wsc, bsc, (const char*)ws, (float*)d_out);
}

// Round 5
// 195.600 us; speedup vs baseline: 8.4974x; 8.4974x over previous
//
#include <hip/hip_runtime.h>
#include <hip/hip_bf16.h>

// MPNScoreModule: B=8 graphs, N=64 nodes, E=256 edges, L=128, S=2 steps.
// Round 5: proven fp32-I/O scaffold (round 4) + MFMA GEMM phases (rounds 1-2).
// One block per (graph g, dest-copy d); full state in LDS; GEMMs via
// mfma_f32_16x16x32_bf16 in transposed form: D[f][col] = W^T[f][k]*Act[col][k],
// A = pre-transposed bf16 weights, B = activations k-contiguous from LDS.
// C-layout (col=lane&15, row=quad*4+reg) -> each lane holds 4 consecutive
// features of one edge/node -> b64 epilogues; in-place residual updates are
// hazard-free because each wave pre-loads its B-fragments before writing.

typedef __attribute__((ext_vector_type(8))) __bf16 bf16x8;
typedef __attribute__((ext_vector_type(4))) __bf16 bf16x4;
typedef __attribute__((ext_vector_type(4))) float  floatx4;

#define MFMA16(a, b, c) __builtin_amdgcn_mfma_f32_16x16x32_bf16((a), (b), (c), 0, 0, 0)

__device__ __forceinline__ float leaky(float x) { return x > 0.f ? x : 0.01f * x; }

// ---- workspace layout (bytes) ----
#define WS_WT     0          // bf16 [10][128][128] transposed weights (s*5 + {W1,W2,W3,Wn1,Wn2}), [f][k]
#define WS_XAP    327680     // f32  [8][64][128]  x @ Wne[0:128] + b_node_enc
#define WS_XDP    589824     // f32  [8][64][128]  x @ Wne[128:256]
#define WS_EE0    851968     // bf16 [8][256][128] leaky(edge_attr @ Wee + b)
#define WS_CE     1376256    // f32  [8][2][128]   gg @ W4  + b_edge_upd
#define WS_CN     1384448    // f32  [8][2][128]   gg @ Wn3 + b_node_upd
#define WS_CSROFF 1392640    // int  [8][72]
#define WS_CSREID 1394944    // int  [8][256]
// end ~1.4 MB

#define LDE 136   // padded LDS row stride (elements)

// ============================ prep kernel ============================
__global__ __launch_bounds__(256) void mpn_prep(
    const float* __restrict__ x,     // [8][64][128]
    const float* __restrict__ ea,    // [8][256][128]
    const float* __restrict__ u,     // [8][128]
    const int*   __restrict__ eidx,  // [8][2][256]
    const float* __restrict__ Wne,   // [257][128]
    const float* __restrict__ bne,   // [128]
    const float* __restrict__ Wee,   // [128][128]
    const float* __restrict__ bee,   // [128]
    const float* __restrict__ Wge,   // [128][128]
    const float* __restrict__ bge,   // [128]
    const float* __restrict__ Weu,   // [2][512][128]
    const float* __restrict__ beu,   // [2][128]
    const float* __restrict__ Wnu,   // [2][384][128]
    const float* __restrict__ bnu,   // [2][128]
    char* __restrict__ ws)
{
  const int b = blockIdx.x, tid = threadIdx.x;
  __bf16* wt  = (__bf16*)(ws + WS_WT);
  float*  xap = (float*)(ws + WS_XAP);
  float*  xdp = (float*)(ws + WS_XDP);
  __bf16* ee0 = (__bf16*)(ws + WS_EE0);
  float*  cev = (float*)(ws + WS_CE);
  float*  cnv = (float*)(ws + WS_CN);
  int* csroff = (int*)(ws + WS_CSROFF);
  int* csreid = (int*)(ws + WS_CSREID);

  if (b < 20) {
    // transpose the 10 [128][128] weight blocks: wt[m][f][k] = src[k][f] (bf16)
    const int m = b >> 1, half = b & 1;
    const int s = m / 5, t = m % 5;
    const float* src = (t < 3) ? (Weu + (size_t)(s*512 + t*128)*128)
                               : (Wnu + (size_t)(s*384 + (t-3)*128)*128);
    const int f = half*64 + (tid & 63);
    const int kq = tid >> 6;
    for (int j = 0; j < 32; ++j) {
      int k = kq*32 + j;
      wt[m*16384 + f*128 + k] = (__bf16)src[k*128 + f];
    }
  } else if (b < 28) {
    // per-graph: gg, ce/cn constant vectors, CSR (deterministic)
    const int g = b - 20;
    __shared__ float gg_sh[128];
    __shared__ int dst_sh[256];
    __shared__ int cnt_sh[64];
    __shared__ int off_sh[65];
    if (tid < 128) {
      float acc = bge[tid];
      for (int k = 0; k < 128; ++k)
        acc += u[g*128 + k] * Wge[k*128 + tid];
      gg_sh[tid] = leaky(acc);
    }
    dst_sh[tid] = eidx[g*512 + 256 + tid];
    __syncthreads();
    {
      const int s = tid >> 7, f = tid & 127;
      float ac = beu[s*128 + f];
      float an = bnu[s*128 + f];
      for (int k = 0; k < 128; ++k) {
        float gk = gg_sh[k];
        ac += gk * Weu[(s*512 + 384 + k)*128 + f];
        an += gk * Wnu[(s*384 + 256 + k)*128 + f];
      }
      cev[(g*2 + s)*128 + f] = ac;
      cnv[(g*2 + s)*128 + f] = an;
    }
    if (tid < 64) {
      int c = 0;
      for (int e = 0; e < 256; ++e) c += (dst_sh[e] == tid) ? 1 : 0;
      cnt_sh[tid] = c;
    }
    __syncthreads();
    if (tid == 0) {
      int o = 0;
      for (int n = 0; n < 64; ++n) { off_sh[n] = o; o += cnt_sh[n]; }
      off_sh[64] = o;
    }
    __syncthreads();
    if (tid < 65) csroff[g*72 + tid] = off_sh[tid];
    if (tid < 64) {
      int o = off_sh[tid];
      for (int e = 0; e < 256; ++e)
        if (dst_sh[e] == tid) csreid[g*256 + (o++)] = e;
    }
  } else {
    // encoders: ee0 (16 blocks/graph), xap (4), xdp (4)
    const int bb = b - 28;
    const int g = bb / 24, r = bb % 24;
    const int f = tid & 127, rh = tid >> 7;
    if (r < 16) {
      const int row0 = r*16;
      for (int jj = 0; jj < 8; ++jj) {
        int row = row0 + rh + 2*jj;
        float acc = bee[f];
        for (int k = 0; k < 128; ++k)
          acc += ea[(g*256 + row)*128 + k] * Wee[k*128 + f];
        ee0[(g*256 + row)*128 + f] = (__bf16)leaky(acc);
      }
    } else if (r < 20) {
      const int row0 = (r - 16)*16;
      for (int jj = 0; jj < 8; ++jj) {
        int row = row0 + rh + 2*jj;
        float acc = bne[f];
        for (int k = 0; k < 128; ++k)
          acc += x[(g*64 + row)*128 + k] * Wne[k*128 + f];
        xap[(g*64 + row)*128 + f] = acc;
      }
    } else {
      const int row0 = (r - 20)*16;
      for (int jj = 0; jj < 8; ++jj) {
        int row = row0 + rh + 2*jj;
        float acc = 0.f;
        for (int k = 0; k < 128; ++k)
          acc += x[(g*64 + row)*128 + k] * Wne[(128 + k)*128 + f];
        xdp[(g*64 + row)*128 + f] = acc;
      }
    }
  }
}

// ============================ main kernel ============================
__global__ __launch_bounds__(256, 1) void mpn_main(
    const float* __restrict__ spdist,  // [8][64][64]
    const int*   __restrict__ eidx,    // [8][2][256]
    const float* __restrict__ Wne,     // row 256 = spdist weight
    const float* __restrict__ wscore,  // [128]
    const float* __restrict__ bscore,  // [1]
    const char* __restrict__ ws,
    float* __restrict__ out)           // [8][256][64]  (g*16384 + e*64 + d), fp32
{
  __shared__ __align__(16) __bf16 s_ee[256*LDE];   // edge state
  __shared__ __align__(16) __bf16 s_h [64*LDE];    // node state
  __shared__ __align__(16) __bf16 s_p2[64*LDE];    // h@W2 (reused as agg)
  __shared__ __align__(16) __bf16 s_p3[64*LDE];    // h@W3 + ce
  __shared__ int s_off[65];
  __shared__ int s_eid[256];

  const __bf16* wt  = (const __bf16*)(ws + WS_WT);
  const float*  xap = (const float*)(ws + WS_XAP);
  const float*  xdp = (const float*)(ws + WS_XDP);
  const __bf16* ee0 = (const __bf16*)(ws + WS_EE0);
  const float*  cev = (const float*)(ws + WS_CE);
  const float*  cnv = (const float*)(ws + WS_CN);
  const int* csroff = (const int*)(ws + WS_CSROFF);
  const int* csreid = (const int*)(ws + WS_CSREID);

  const int tid = threadIdx.x;
  const int w = tid >> 6, l = tid & 63;
  const int q = l >> 4, xn = l & 15;
  const int g = blockIdx.x >> 6, d = blockIdx.x & 63;

  if (tid < 65) s_off[tid] = csroff[g*72 + tid];
  s_eid[tid] = csreid[g*256 + tid];

  // node encoder: h[i][f] = leaky(xap[i][f] + xdp[d][f] + sp(d,i)*wsp[f])
  {
    const int f = tid & 127, ib = tid >> 7;
    float xdpv = xdp[(g*64 + d)*128 + f];
    float wspv = Wne[256*128 + f];
    #pragma unroll
    for (int j = 0; j < 32; ++j) {
      int i = ib + 2*j;
      float sp = spdist[(g*64 + d)*64 + i];
      float v = xap[(g*64 + i)*128 + f] + xdpv + sp*wspv;
      s_h[i*LDE + f] = (__bf16)leaky(v);
    }
  }
  // stage ee0 -> LDS
  #pragma unroll
  for (int it = 0; it < 16; ++it) {
    int c = it*256 + tid;
    int row = c >> 4, col = c & 15;
    *(bf16x8*)&s_ee[row*LDE + col*8] = *(const bf16x8*)&ee0[(g*256 + row)*128 + col*8];
  }

  int mySrc[4], myDst[4];
  #pragma unroll
  for (int t = 0; t < 4; ++t) {
    int e = w*64 + t*16 + xn;
    mySrc[t] = eidx[g*512 + e];
    myDst[t] = eidx[g*512 + 256 + e];
  }
  __syncthreads();

  for (int s = 0; s < 2; ++s) {
    const __bf16* W1T = wt + (s*5 + 0)*16384;
    const __bf16* W2T = wt + (s*5 + 1)*16384;
    const __bf16* W3T = wt + (s*5 + 2)*16384;
    const __bf16* N1T = wt + (s*5 + 3)*16384;
    const __bf16* N2T = wt + (s*5 + 4)*16384;

    // ---- phase 1: s_p2 = h@W2 ; s_p3 = h@W3 + ce  (wave w owns nodes 16w..16w+15)
    {
      bf16x8 bh[4];
      const int i = w*16 + xn;
      #pragma unroll
      for (int c = 0; c < 4; ++c)
        bh[c] = *(const bf16x8*)&s_h[i*LDE + c*32 + q*8];
      #pragma unroll
      for (int m = 0; m < 8; ++m) {
        floatx4 a2 = (floatx4)0.f, a3 = (floatx4)0.f;
        const int fr = m*16 + xn;
        #pragma unroll
        for (int c = 0; c < 4; ++c) {
          bf16x8 aw = *(const bf16x8*)&W2T[fr*128 + c*32 + q*8];
          a2 = MFMA16(aw, bh[c], a2);
        }
        #pragma unroll
        for (int c = 0; c < 4; ++c) {
          bf16x8 aw = *(const bf16x8*)&W3T[fr*128 + c*32 + q*8];
          a3 = MFMA16(aw, bh[c], a3);
        }
        const int f0 = m*16 + q*4;
        floatx4 ce4 = *(const floatx4*)&cev[(g*2 + s)*128 + f0];
        bf16x4 o2, o3;
        #pragma unroll
        for (int r = 0; r < 4; ++r) { o2[r] = (__bf16)a2[r]; o3[r] = (__bf16)(a3[r] + ce4[r]); }
        *(bf16x4*)&s_p2[i*LDE + f0] = o2;
        *(bf16x4*)&s_p3[i*LDE + f0] = o3;
      }
    }
    __syncthreads();

    // ---- phase 2: ee += leaky(ee@W1 + p2[src] + p3[dst])  (wave w owns edges 64w..64w+63;
    //      B-fragments pre-loaded so the in-place update is hazard-free)
    {
      bf16x8 be[4][4];
      #pragma unroll
      for (int t = 0; t < 4; ++t) {
        int e = w*64 + t*16 + xn;
        #pragma unroll
        for (int c = 0; c < 4; ++c)
          be[t][c] = *(const bf16x8*)&s_ee[e*LDE + c*32 + q*8];
      }
      #pragma unroll
      for (int m = 0; m < 8; ++m) {
        floatx4 acc[4];
        #pragma unroll
        for (int t = 0; t < 4; ++t) acc[t] = (floatx4)0.f;
        const int fr = m*16 + xn;
        #pragma unroll
        for (int c = 0; c < 4; ++c) {
          bf16x8 aw = *(const bf16x8*)&W1T[fr*128 + c*32 + q*8];
          #pragma unroll
          for (int t = 0; t < 4; ++t) acc[t] = MFMA16(aw, be[t][c], acc[t]);
        }
        const int f0 = m*16 + q*4;
        #pragma unroll
        for (int t = 0; t < 4; ++t) {
          int e = w*64 + t*16 + xn;
          bf16x4 old = *(const bf16x4*)&s_ee[e*LDE + f0];
          bf16x4 v2  = *(const bf16x4*)&s_p2[mySrc[t]*LDE + f0];
          bf16x4 v3  = *(const bf16x4*)&s_p3[myDst[t]*LDE + f0];
          bf16x4 res;
          #pragma unroll
          for (int r = 0; r < 4; ++r) {
            float vv = acc[t][r] + (float)v2[r] + (float)v3[r];
            res[r] = (__bf16)((float)old[r] + leaky(vv));
          }
          *(bf16x4*)&s_ee[e*LDE + f0] = res;
        }
      }
    }
    __syncthreads();

    if (s == 0) {  // last step's node update is unused -> skip
      // ---- phase 3: agg = segment_sum(ee, dst) -> s_p2 (bf16)
      {
        const int node = w*16 + (l >> 2);
        const int fs = (l & 3)*32;
        float av[32];
        #pragma unroll
        for (int j = 0; j < 32; ++j) av[j] = 0.f;
        const int b0 = s_off[node], b1 = s_off[node + 1];
        for (int idx = b0; idx < b1; ++idx) {
          int e = s_eid[idx];
          #pragma unroll
          for (int cc = 0; cc < 4; ++cc) {
            bf16x8 vv = *(const bf16x8*)&s_ee[e*LDE + fs + cc*8];
            #pragma unroll
            for (int j = 0; j < 8; ++j) av[cc*8 + j] += (float)vv[j];
          }
        }
        #pragma unroll
        for (int cc = 0; cc < 4; ++cc) {
          bf16x8 o;
          #pragma unroll
          for (int j = 0; j < 8; ++j) o[j] = (__bf16)av[cc*8 + j];
          *(bf16x8*)&s_p2[node*LDE + fs + cc*8] = o;
        }
      }
      __syncthreads();
      // ---- phase 4: h += leaky(h@Wn1 + agg@Wn2 + cn)  (in-place; B pre-loaded)
      {
        bf16x8 bh[4], bg[4];
        const int i = w*16 + xn;
        #pragma unroll
        for (int c = 0; c < 4; ++c) {
          bh[c] = *(const bf16x8*)&s_h[i*LDE + c*32 + q*8];
          bg[c] = *(const bf16x8*)&s_p2[i*LDE + c*32 + q*8];
        }
        #pragma unroll
        for (int m = 0; m < 8; ++m) {
          floatx4 acc = (floatx4)0.f;
          const int fr = m*16 + xn;
          #pragma unroll
          for (int c = 0; c < 4; ++c) {
            bf16x8 aw = *(const bf16x8*)&N1T[fr*128 + c*32 + q*8];
            acc = MFMA16(aw, bh[c], acc);
          }
          #pragma unroll
          for (int c = 0; c < 4; ++c) {
            bf16x8 aw = *(const bf16x8*)&N2T[fr*128 + c*32 + q*8];
            acc = MFMA16(aw, bg[c], acc);
          }
          const int f0 = m*16 + q*4;
          floatx4 cn4 = *(const floatx4*)&cnv[(g*2 + s)*128 + f0];
          bf16x4 old = *(const bf16x4*)&s_h[i*LDE + f0];
          bf16x4 res;
          #pragma unroll
          for (int r = 0; r < 4; ++r)
            res[r] = (__bf16)((float)old[r] + leaky(acc[r] + cn4[r]));
          *(bf16x4*)&s_h[i*LDE + f0] = res;
        }
      }
      __syncthreads();
    }
  }

  // ---- scores: out[g, e, d] = ee[e] . wscore + b  (fp32 output)
  {
    const int e = w*64 + l;
    float acc = bscore[0];
    #pragma unroll
    for (int c = 0; c < 16; ++c) {
      bf16x8 vv = *(const bf16x8*)&s_ee[e*LDE + c*8];
      #pragma unroll
      for (int j = 0; j < 8; ++j) acc += (float)vv[j] * wscore[c*8 + j];
    }
    out[g*16384 + e*64 + d] = acc;
  }
}

extern "C" void kernel_launch(void* const* d_in, const int* in_sizes, int n_in,
                              void* d_out, int out_size, void* d_ws, size_t ws_size,
                              hipStream_t stream) {
  (void)in_sizes; (void)n_in; (void)out_size; (void)ws_size;
  const float* x   = (const float*)d_in[0];
  const float* ea  = (const float*)d_in[1];
  const float* u   = (const float*)d_in[2];
  const float* sp  = (const float*)d_in[3];
  const int*   ei  = (const int*)d_in[4];
  const float* Wne = (const float*)d_in[5];
  const float* bne = (const float*)d_in[6];
  const float* Wee = (const float*)d_in[7];
  const float* bee = (const float*)d_in[8];
  const float* Wge = (const float*)d_in[9];
  const float* bge = (const float*)d_in[10];
  const float* Weu = (const float*)d_in[11];
  const float* beu = (const float*)d_in[12];
  const float* Wnu = (const float*)d_in[13];
  const float* bnu = (const float*)d_in[14];
  const float* Wsc = (const float*)d_in[15];
  const float* bsc = (const float*)d_in[16];
  char* ws = (char*)d_ws;

  hipLaunchKernelGGL(mpn_prep, dim3(220), dim3(256), 0, stream,
                     x, ea, u, ei, Wne, bne, Wee, bee, Wge, bge, Weu, beu, Wnu, bnu, ws);
  hipLaunchKernelGGL(mpn_main, dim3(512), dim3(256), 0, stream,
                     sp, ei, Wne, Wsc, bsc, (const char*)ws, (float*)d_out);
}